// Round 12
// baseline (196.209 us; speedup 1.0000x reference)
//
#include <hip/hip_runtime.h>
#include <hip/hip_bf16.h>

#define SS 512
#define BATCH 2048
#define GL 32
#define OL 20
#define MM 32
#define CC 16
#define GM 64
#define OM 20
#define GR 128
#define ORR 38
#define IMID 384
#define IROOT 768
#define EPSBN 1e-5f

#define KSPLIT 16
#define KCH 48            // 768 / 16

// ---- workspace layout (floats) ----
// child is TRANSPOSED: [s][o][b]; hm is TRANSPOSED: [(m*20+o)][b]
#define SZ_CHILD ((size_t)SS * OL * BATCH)
#define OFF_SCL  (SZ_CHILD)
#define OFF_SHL  (OFF_SCL + (size_t)SS * OL)
#define OFF_HM   (OFF_SHL + (size_t)SS * OL)
#define OFF_MP   (OFF_HM + (size_t)MM * OM * BATCH)
#define OFF_HR   (OFF_MP + (size_t)MM * 32 * 2 * OM)
#define OFF_RP   (OFF_HR + (size_t)BATCH * ORR)
#define OFF_SCM  (OFF_RP + (size_t)32 * 76)
#define OFF_SHM  (OFF_SCM + (size_t)MM * OM)
#define OFF_PW   (OFF_SHM + (size_t)MM * OM)     // KSPLIT*2048*38 floats

// Branch-free inline tanh: no OCML call, ~6 VALU instrs, |err| ~1e-6.
__device__ __forceinline__ float tanh_fast(float x) {
  float ax = fabsf(x);
  float e  = __expf(-2.0f * ax);
  float r  = __fdividef(1.0f - e, 1.0f + e);
  return copysignf(r, x);
}

#define FMA20(xs, wptr, acc) do { \
  const float4* _wr = (const float4*)(wptr); \
  float4 _w0=_wr[0], _w1=_wr[1], _w2=_wr[2], _w3=_wr[3], _w4=_wr[4]; \
  acc[0]=fmaf(xs,_w0.x,acc[0]);  acc[1]=fmaf(xs,_w0.y,acc[1]); \
  acc[2]=fmaf(xs,_w0.z,acc[2]);  acc[3]=fmaf(xs,_w0.w,acc[3]); \
  acc[4]=fmaf(xs,_w1.x,acc[4]);  acc[5]=fmaf(xs,_w1.y,acc[5]); \
  acc[6]=fmaf(xs,_w1.z,acc[6]);  acc[7]=fmaf(xs,_w1.w,acc[7]); \
  acc[8]=fmaf(xs,_w2.x,acc[8]);  acc[9]=fmaf(xs,_w2.y,acc[9]); \
  acc[10]=fmaf(xs,_w2.z,acc[10]); acc[11]=fmaf(xs,_w2.w,acc[11]); \
  acc[12]=fmaf(xs,_w3.x,acc[12]); acc[13]=fmaf(xs,_w3.y,acc[13]); \
  acc[14]=fmaf(xs,_w3.z,acc[14]); acc[15]=fmaf(xs,_w3.w,acc[15]); \
  acc[16]=fmaf(xs,_w4.x,acc[16]); acc[17]=fmaf(xs,_w4.y,acc[17]); \
  acc[18]=fmaf(xs,_w4.z,acc[18]); acc[19]=fmaf(xs,_w4.w,acc[19]); \
} while (0)

// ---------------- leaf: x staged in LDS; W read UNIFORM from global ---------
// r11 structure, one change: W/bias are block-uniform -> read directly from
// global (compiler emits scalar s_loads / L1-broadcast vector loads) instead
// of LDS. Removes the 5x ds_read_b128 per 20 FMAs that made the kernel
// LDS-pipe-bound (r11: occupancy 21->41% gave no speedup; LDS is CU-shared).
__global__ __launch_bounds__(512, 1) void k_leaf(
    const float* __restrict__ x, const float* __restrict__ W,
    const float* __restrict__ bias, const float* __restrict__ g,
    const float* __restrict__ be, float* __restrict__ child,
    float* __restrict__ scL, float* __restrict__ shL)
{
  const int s = blockIdx.x;
  const int t = threadIdx.x;
  __shared__ float xb[512 * 17];      // 34816 B, stride 17 odd -> conflict-free
  __shared__ float red[8][2 * OL];

  const float* __restrict__ Ws = W + (size_t)s * GL * OL;   // block-uniform
  const float* __restrict__ bs = bias + s * OL;             // block-uniform

  float sum[OL], ssq[OL];
#pragma unroll
  for (int o = 0; o < OL; o++) { sum[o] = 0.f; ssq[o] = 0.f; }

#pragma unroll 1
  for (int rr = 0; rr < 4; rr++) {
    const float4* src = (const float4*)(x + ((size_t)s * BATCH + rr * 512) * GL);
    float acc[OL];
#pragma unroll
    for (int o = 0; o < OL; o++) acc[o] = 0.f;

    // ---- K half 0 (k = 0..15) ----
#pragma unroll
    for (int j = 0; j < 4; j++) {
      const int f2 = t + j * 512;        // 0..2047
      const int r = f2 >> 2, q = f2 & 3;
      float4 v = src[r * 8 + q];         // first half of row r
      float* wp = &xb[r * 17 + q * 4];
      wp[0] = v.x; wp[1] = v.y; wp[2] = v.z; wp[3] = v.w;
    }
    __syncthreads();
    {
      const float* xrow = &xb[t * 17];
#pragma unroll
      for (int k = 0; k < 16; k++) {
        FMA20(xrow[k], Ws + k * OL, acc);
      }
    }
    __syncthreads();

    // ---- K half 1 (k = 16..31) ----
#pragma unroll
    for (int j = 0; j < 4; j++) {
      const int f2 = t + j * 512;
      const int r = f2 >> 2, q = f2 & 3;
      float4 v = src[r * 8 + 4 + q];     // second half of row r
      float* wp = &xb[r * 17 + q * 4];
      wp[0] = v.x; wp[1] = v.y; wp[2] = v.z; wp[3] = v.w;
    }
    __syncthreads();
    {
      const float* xrow = &xb[t * 17];
#pragma unroll
      for (int k = 0; k < 16; k++) {
        FMA20(xrow[k], Ws + (16 + k) * OL, acc);
      }
    }

    const int b = rr * 512 + t;
#pragma unroll
    for (int o = 0; o < OL; o++) {
      float hv = tanh_fast(acc[o] + bs[o]);
      sum[o] += hv;
      ssq[o] = fmaf(hv, hv, ssq[o]);
      child[((size_t)s * OL + o) * BATCH + b] = hv;   // coalesced
    }
    __syncthreads();   // xb reused next rr
  }

  const int wave = t >> 6, lane = t & 63;
#pragma unroll
  for (int o = 0; o < OL; o++) {
    float s1 = sum[o], s2 = ssq[o];
#pragma unroll
    for (int d = 32; d >= 1; d >>= 1) { s1 += __shfl_xor(s1, d); s2 += __shfl_xor(s2, d); }
    if (lane == 0) { red[wave][o] = s1; red[wave][OL + o] = s2; }
  }
  __syncthreads();
  if (t < 2 * OL) {
    float v = 0.f;
#pragma unroll
    for (int w2 = 0; w2 < 8; w2++) v += red[w2][t];
    red[0][t] = v;
  }
  __syncthreads();
  if (t < OL) {
    float mean = red[0][t] * (1.f / BATCH);
    float var  = red[0][OL + t] * (1.f / BATCH) - mean * mean;
    float rs = rsqrtf(var + EPSBN);
    float sc = g[s * OL + t] * rs;
    scL[s * OL + t] = sc;
    shL[s * OL + t] = be[s * OL + t] - mean * sc;
  }
}

// ---------------- mid: coalesced transposed child reads; transposed hm out --
__global__ __launch_bounds__(256, 2) void k_mid(
    const float* __restrict__ xg, const float* __restrict__ child,
    const float* __restrict__ scL, const float* __restrict__ shL,
    const float* __restrict__ W, const float* __restrict__ bias,
    float* __restrict__ hm, float* __restrict__ mp)
{
  const int chunk = blockIdx.x;
  const int m = blockIdx.y;
  const int t = threadIdx.x;
  const int kq = t >> 6;
  const int lane = t & 63;
  const int b = chunk * 64 + lane;

  __shared__ float Wl[IMID * OM];
  __shared__ float cb[3][64][21];
  __shared__ float scs[CC * OL];
  __shared__ float shs[CC * OL];
  __shared__ float xgb[64 * 69];

  for (int i = t; i < IMID * OM / 4; i += 256)
    ((float4*)Wl)[i] = ((const float4*)(W + (size_t)m * IMID * OM))[i];
  if (t < 80)       ((float4*)scs)[t]      = ((const float4*)(scL + m * CC * OL))[t];
  else if (t < 160) ((float4*)shs)[t - 80] = ((const float4*)(shL + m * CC * OL))[t - 80];

  {
    const float4* gs = (const float4*)(xg + ((size_t)m * BATCH + chunk * 64) * GM);
#pragma unroll
    for (int j = 0; j < 4; j++) {
      const int f = t + j * 256;
      float4 v = gs[f];
      const int r = f >> 4, c4 = (f & 15) << 2;
      float* wp = &xgb[r * 69 + c4];
      wp[0] = v.x; wp[1] = v.y; wp[2] = v.z; wp[3] = v.w;
    }
  }
  __syncthreads();

  float acc[OM];
#pragma unroll
  for (int o = 0; o < OM; o++) acc[o] = 0.f;

  const float* grow = &xgb[lane * 69 + kq * 16];
#pragma unroll
  for (int k = 0; k < 16; k++) {
    FMA20(grow[k], &Wl[(kq * 16 + k) * OM], acc);
  }
#pragma unroll 1
  for (int ci = 0; ci < 4; ci++) {
    const int c = kq * 4 + ci;
    const float* cbase = child + ((size_t)(m * CC + c) * OL) * BATCH + b;
#pragma unroll
    for (int o = 0; o < OL; o++) {
      float v = cbase[(size_t)o * BATCH];
      float xv = fmaf(v, scs[c * OL + o], shs[c * OL + o]);
      FMA20(xv, &Wl[(GM + c * OL + o) * OM], acc);
    }
  }

  if (kq > 0) {
#pragma unroll
    for (int o = 0; o < OM; o++) cb[kq - 1][lane][o] = acc[o];
  }
  __syncthreads();

  if (kq == 0) {
#pragma unroll
    for (int o = 0; o < OM; o++) {
      float v = acc[o] + cb[0][lane][o] + cb[1][lane][o] + cb[2][lane][o] + bias[m * OM + o];
      acc[o] = tanh_fast(v);
    }
#pragma unroll
    for (int o = 0; o < OM; o++)
      hm[((size_t)m * OM + o) * BATCH + b] = acc[o];
#pragma unroll
    for (int o = 0; o < OM; o++) {
      float s1 = acc[o], s2 = acc[o] * acc[o];
#pragma unroll
      for (int d = 32; d >= 1; d >>= 1) { s1 += __shfl_xor(s1, d); s2 += __shfl_xor(s2, d); }
      if (lane == 0) {
        mp[((size_t)m * 32 + chunk) * (2 * OM) + o] = s1;
        mp[((size_t)m * 32 + chunk) * (2 * OM) + OM + o] = s2;
      }
    }
  }
}

// ---------------- mid BN affine finalize (tiny) -----------------------------
__global__ __launch_bounds__(256) void k_midstats(
    const float* __restrict__ mp, const float* __restrict__ g_mid,
    const float* __restrict__ be_mid,
    float* __restrict__ scm, float* __restrict__ shm)
{
  const int e = blockIdx.x * 256 + threadIdx.x;
  if (e >= MM * OM) return;
  const int m = e / OM, o = e % OM;
  float s1 = 0.f, s2 = 0.f;
  for (int c = 0; c < 32; c++) {
    s1 += mp[((size_t)m * 32 + c) * (2 * OM) + o];
    s2 += mp[((size_t)m * 32 + c) * (2 * OM) + OM + o];
  }
  float mean = s1 * (1.f / BATCH);
  float var  = s2 * (1.f / BATCH) - mean * mean;
  float r = rsqrtf(var + EPSBN);
  float sc = g_mid[e] * r;
  scm[e] = sc;
  shm[e] = be_mid[e] - mean * sc;
}

// ---------------- root partial GEMM: K split 16 ways ------------------------
__global__ __launch_bounds__(256, 2) void k_root_partial(
    const float* __restrict__ xr, const float* __restrict__ hm,
    const float* __restrict__ scm, const float* __restrict__ shm,
    const float* __restrict__ W, float* __restrict__ pw)
{
  const int rc = blockIdx.x;      // 0..31
  const int kc = blockIdx.y;      // 0..15
  const int t = threadIdx.x;
  const int w = t >> 6, lane = t & 63;
  const int ob = w * 10;
  const bool full = (w < 3);
  const int b = rc * 64 + lane;
  const int k0 = kc * KCH;

  __shared__ float Wl[KCH * ORR];
  __shared__ float scs[KCH], shs[KCH];

  for (int i = t; i < KCH * ORR; i += 256)
    Wl[i] = W[(size_t)k0 * ORR + i];
  if (t < KCH) {
    const int mi = k0 + t - GR;
    const bool v = (mi >= 0);
    scs[t] = v ? scm[mi] : 0.f;
    shs[t] = v ? shm[mi] : 0.f;
  }
  __syncthreads();

  float acc[10];
#pragma unroll
  for (int j = 0; j < 10; j++) acc[j] = 0.f;

#define FMA10(xs, kk) do { \
    const float2* wr = (const float2*)(Wl + (size_t)(kk) * ORR + ob); \
    float2 w0 = wr[0], w1 = wr[1], w2 = wr[2], w3 = wr[3]; \
    float2 w4 = full ? wr[4] : make_float2(0.f, 0.f); \
    acc[0]=fmaf(xs,w0.x,acc[0]); acc[1]=fmaf(xs,w0.y,acc[1]); \
    acc[2]=fmaf(xs,w1.x,acc[2]); acc[3]=fmaf(xs,w1.y,acc[3]); \
    acc[4]=fmaf(xs,w2.x,acc[4]); acc[5]=fmaf(xs,w2.y,acc[5]); \
    acc[6]=fmaf(xs,w3.x,acc[6]); acc[7]=fmaf(xs,w3.y,acc[7]); \
    acc[8]=fmaf(xs,w4.x,acc[8]); acc[9]=fmaf(xs,w4.y,acc[9]); \
  } while (0)

#pragma unroll 2
  for (int g = 0; g < KCH / 4; g++) {
    const int k = k0 + g * 4;
    float xa[4];
    if (k < GR) {
      float4 xv = *(const float4*)(xr + (size_t)b * GR + k);
      xa[0] = xv.x; xa[1] = xv.y; xa[2] = xv.z; xa[3] = xv.w;
    } else {
      const int mi = k - GR;
      const float* hp = hm + (size_t)mi * BATCH + b;
      const int lk = g * 4;
#pragma unroll
      for (int j = 0; j < 4; j++)
        xa[j] = fmaf(hp[(size_t)j * BATCH], scs[lk + j], shs[lk + j]);
    }
#pragma unroll
    for (int j = 0; j < 4; j++) FMA10(xa[j], g * 4 + j);
  }
#undef FMA10

  const size_t base = ((size_t)kc * BATCH + b) * ORR + ob;
#pragma unroll
  for (int j = 0; j < 10; j++)
    if (j < 8 || full) pw[base + j] = acc[j];
}

// ---------------- root finalize: sum partials + bias + tanh + BN partials ---
__global__ __launch_bounds__(256) void k_rootfinal(
    const float* __restrict__ pw, const float* __restrict__ bias,
    float* __restrict__ hr, float* __restrict__ rp)
{
  const int blk = blockIdx.x;     // 0..31
  const int t = threadIdx.x;
  const int w = t >> 6, lane = t & 63;
  const int ob = w * 10;
  const bool full = (w < 3);
  const int b = blk * 64 + lane;

  float acc[10];
#pragma unroll
  for (int j = 0; j < 10; j++) acc[j] = 0.f;

#pragma unroll 1
  for (int kc = 0; kc < KSPLIT; kc++) {
    const size_t base = ((size_t)kc * BATCH + b) * ORR + ob;
#pragma unroll
    for (int j = 0; j < 10; j++)
      if (j < 8 || full) acc[j] += pw[base + j];
  }

#pragma unroll
  for (int j = 0; j < 10; j++) {
    float bj = (j < 8 || full) ? bias[ob + j] : 0.f;
    acc[j] = tanh_fast(acc[j] + bj);
  }

#pragma unroll
  for (int j = 0; j < 10; j++) {
    float s1 = acc[j], s2 = acc[j] * acc[j];
#pragma unroll
    for (int d = 32; d >= 1; d >>= 1) { s1 += __shfl_xor(s1, d); s2 += __shfl_xor(s2, d); }
    if (lane == 0 && (j < 8 || full)) {
      rp[blk * 76 + ob + j] = s1;
      rp[blk * 76 + ORR + ob + j] = s2;
    }
  }
#pragma unroll
  for (int j = 0; j < 10; j++)
    if (j < 8 || full) hr[(size_t)b * ORR + ob + j] = acc[j];
}

// ---------------- root BN finalize -> output --------------------------------
__global__ __launch_bounds__(256) void k_rootnorm(
    const float* __restrict__ hr, const float* __restrict__ rp,
    const float* __restrict__ g, const float* __restrict__ be,
    float* __restrict__ out)
{
  __shared__ float sc[ORR], sh[ORR];
  const int t = threadIdx.x;
  if (t < ORR) {
    float s1 = 0.f, s2 = 0.f;
    for (int blk = 0; blk < 32; blk++) {
      s1 += rp[blk * 76 + t];
      s2 += rp[blk * 76 + ORR + t];
    }
    float mean = s1 * (1.f / BATCH);
    float var  = s2 * (1.f / BATCH) - mean * mean;
    float r = rsqrtf(var + EPSBN);
    float scv = g[t] * r;
    sc[t] = scv;
    sh[t] = be[t] - mean * scv;
  }
  __syncthreads();
  const int idx = blockIdx.x * 256 + t;   // 304*256 = 77824 exactly
  const int o = idx % ORR;
  out[idx] = hr[idx] * sc[o] + sh[o];
}

extern "C" void kernel_launch(void* const* d_in, const int* in_sizes, int n_in,
                              void* d_out, int out_size, void* d_ws, size_t ws_size,
                              hipStream_t stream) {
  (void)in_sizes; (void)n_in; (void)out_size; (void)ws_size;
  const float* x_leaf  = (const float*)d_in[0];
  const float* x_mid   = (const float*)d_in[1];
  const float* x_root  = (const float*)d_in[2];
  const float* W_leaf  = (const float*)d_in[3];
  const float* b_leaf  = (const float*)d_in[4];
  const float* g_leaf  = (const float*)d_in[5];
  const float* be_leaf = (const float*)d_in[6];
  const float* W_mid   = (const float*)d_in[7];
  const float* b_mid   = (const float*)d_in[8];
  const float* g_mid   = (const float*)d_in[9];
  const float* be_mid  = (const float*)d_in[10];
  const float* W_root  = (const float*)d_in[11];
  const float* b_root  = (const float*)d_in[12];
  const float* g_root  = (const float*)d_in[13];
  const float* be_root = (const float*)d_in[14];
  float* out = (float*)d_out;
  float* ws  = (float*)d_ws;

  float* child = ws;
  float* scL   = ws + OFF_SCL;
  float* shL   = ws + OFF_SHL;
  float* hm    = ws + OFF_HM;
  float* mp    = ws + OFF_MP;
  float* hr    = ws + OFF_HR;
  float* rp    = ws + OFF_RP;
  float* scm   = ws + OFF_SCM;
  float* shm   = ws + OFF_SHM;
  float* pw    = ws + OFF_PW;

  k_leaf<<<SS, 512, 0, stream>>>(x_leaf, W_leaf, b_leaf, g_leaf, be_leaf,
                                 child, scL, shL);
  k_mid<<<dim3(32, MM), 256, 0, stream>>>(x_mid, child, scL, shL, W_mid, b_mid,
                                          hm, mp);
  k_midstats<<<3, 256, 0, stream>>>(mp, g_mid, be_mid, scm, shm);
  k_root_partial<<<dim3(32, KSPLIT), 256, 0, stream>>>(x_root, hm, scm, shm,
                                                       W_root, pw);
  k_rootfinal<<<32, 256, 0, stream>>>(pw, b_root, hr, rp);
  k_rootnorm<<<304, 256, 0, stream>>>(hr, rp, g_root, be_root, out);
}

// Round 13
// 148.158 us; speedup vs baseline: 1.3243x; 1.3243x over previous
//
#include <hip/hip_runtime.h>
#include <hip/hip_bf16.h>

#define SS 512
#define BATCH 2048
#define GL 32
#define OL 20
#define MM 32
#define CC 16
#define GM 64
#define OM 20
#define GR 128
#define ORR 38
#define IMID 384
#define IROOT 768
#define EPSBN 1e-5f

#define KSPLIT 16
#define KCH 48            // 768 / 16

// ---- workspace layout (floats) ----
// child is TRANSPOSED: [s][o][b]; hm is TRANSPOSED: [(m*20+o)][b]
#define SZ_CHILD ((size_t)SS * OL * BATCH)
#define OFF_SCL  (SZ_CHILD)
#define OFF_SHL  (OFF_SCL + (size_t)SS * OL)
#define OFF_HM   (OFF_SHL + (size_t)SS * OL)
#define OFF_MP   (OFF_HM + (size_t)MM * OM * BATCH)
#define OFF_HR   (OFF_MP + (size_t)MM * 32 * 2 * OM)
#define OFF_RP   (OFF_HR + (size_t)BATCH * ORR)
#define OFF_SCM  (OFF_RP + (size_t)32 * 76)
#define OFF_SHM  (OFF_SCM + (size_t)MM * OM)
#define OFF_PW   (OFF_SHM + (size_t)MM * OM)     // KSPLIT*2048*38 floats

// Branch-free inline tanh: no OCML call, ~6 VALU instrs, |err| ~1e-6.
__device__ __forceinline__ float tanh_fast(float x) {
  float ax = fabsf(x);
  float e  = __expf(-2.0f * ax);
  float r  = __fdividef(1.0f - e, 1.0f + e);
  return copysignf(r, x);
}

#define FMA20(xs, wptr, acc) do { \
  const float4* _wr = (const float4*)(wptr); \
  float4 _w0=_wr[0], _w1=_wr[1], _w2=_wr[2], _w3=_wr[3], _w4=_wr[4]; \
  acc[0]=fmaf(xs,_w0.x,acc[0]);  acc[1]=fmaf(xs,_w0.y,acc[1]); \
  acc[2]=fmaf(xs,_w0.z,acc[2]);  acc[3]=fmaf(xs,_w0.w,acc[3]); \
  acc[4]=fmaf(xs,_w1.x,acc[4]);  acc[5]=fmaf(xs,_w1.y,acc[5]); \
  acc[6]=fmaf(xs,_w1.z,acc[6]);  acc[7]=fmaf(xs,_w1.w,acc[7]); \
  acc[8]=fmaf(xs,_w2.x,acc[8]);  acc[9]=fmaf(xs,_w2.y,acc[9]); \
  acc[10]=fmaf(xs,_w2.z,acc[10]); acc[11]=fmaf(xs,_w2.w,acc[11]); \
  acc[12]=fmaf(xs,_w3.x,acc[12]); acc[13]=fmaf(xs,_w3.y,acc[13]); \
  acc[14]=fmaf(xs,_w3.z,acc[14]); acc[15]=fmaf(xs,_w3.w,acc[15]); \
  acc[16]=fmaf(xs,_w4.x,acc[16]); acc[17]=fmaf(xs,_w4.y,acc[17]); \
  acc[18]=fmaf(xs,_w4.z,acc[18]); acc[19]=fmaf(xs,_w4.w,acc[19]); \
} while (0)

// Shared-W double FMA20: one LDS W read (5x b128) feeds 40 FMAs.
#define FMA20x2(xs0, acc0, xs1, acc1, wptr) do { \
  const float4* _wr = (const float4*)(wptr); \
  float4 _w0=_wr[0], _w1=_wr[1], _w2=_wr[2], _w3=_wr[3], _w4=_wr[4]; \
  acc0[0]=fmaf(xs0,_w0.x,acc0[0]);   acc1[0]=fmaf(xs1,_w0.x,acc1[0]); \
  acc0[1]=fmaf(xs0,_w0.y,acc0[1]);   acc1[1]=fmaf(xs1,_w0.y,acc1[1]); \
  acc0[2]=fmaf(xs0,_w0.z,acc0[2]);   acc1[2]=fmaf(xs1,_w0.z,acc1[2]); \
  acc0[3]=fmaf(xs0,_w0.w,acc0[3]);   acc1[3]=fmaf(xs1,_w0.w,acc1[3]); \
  acc0[4]=fmaf(xs0,_w1.x,acc0[4]);   acc1[4]=fmaf(xs1,_w1.x,acc1[4]); \
  acc0[5]=fmaf(xs0,_w1.y,acc0[5]);   acc1[5]=fmaf(xs1,_w1.y,acc1[5]); \
  acc0[6]=fmaf(xs0,_w1.z,acc0[6]);   acc1[6]=fmaf(xs1,_w1.z,acc1[6]); \
  acc0[7]=fmaf(xs0,_w1.w,acc0[7]);   acc1[7]=fmaf(xs1,_w1.w,acc1[7]); \
  acc0[8]=fmaf(xs0,_w2.x,acc0[8]);   acc1[8]=fmaf(xs1,_w2.x,acc1[8]); \
  acc0[9]=fmaf(xs0,_w2.y,acc0[9]);   acc1[9]=fmaf(xs1,_w2.y,acc1[9]); \
  acc0[10]=fmaf(xs0,_w2.z,acc0[10]); acc1[10]=fmaf(xs1,_w2.z,acc1[10]); \
  acc0[11]=fmaf(xs0,_w2.w,acc0[11]); acc1[11]=fmaf(xs1,_w2.w,acc1[11]); \
  acc0[12]=fmaf(xs0,_w3.x,acc0[12]); acc1[12]=fmaf(xs1,_w3.x,acc1[12]); \
  acc0[13]=fmaf(xs0,_w3.y,acc0[13]); acc1[13]=fmaf(xs1,_w3.y,acc1[13]); \
  acc0[14]=fmaf(xs0,_w3.z,acc0[14]); acc1[14]=fmaf(xs1,_w3.z,acc1[14]); \
  acc0[15]=fmaf(xs0,_w3.w,acc0[15]); acc1[15]=fmaf(xs1,_w3.w,acc1[15]); \
  acc0[16]=fmaf(xs0,_w4.x,acc0[16]); acc1[16]=fmaf(xs1,_w4.x,acc1[16]); \
  acc0[17]=fmaf(xs0,_w4.y,acc0[17]); acc1[17]=fmaf(xs1,_w4.y,acc1[17]); \
  acc0[18]=fmaf(xs0,_w4.z,acc0[18]); acc1[18]=fmaf(xs1,_w4.z,acc1[18]); \
  acc0[19]=fmaf(xs0,_w4.w,acc0[19]); acc1[19]=fmaf(xs1,_w4.w,acc1[19]); \
} while (0)

// ---------------- leaf: r11 LDS structure + 2 rows/thread W-sharing ---------
// W stays in LDS (r12's global-uniform W regressed: vector-load latency on
// the FMA critical path). 256 threads, thread t computes rows t and t+256 of
// each 512-row phase -> one W read per 40 FMAs (halves LDS-pipe pressure).
// Rows 17t and 17(t+256) differ by 0 mod 32 banks -> both stay 2-lane/bank.
// NO min-occupancy clamp in launch_bounds (r9/r10: clamps caused RA spills).
__global__ __launch_bounds__(256) void k_leaf(
    const float* __restrict__ x, const float* __restrict__ W,
    const float* __restrict__ bias, const float* __restrict__ g,
    const float* __restrict__ be, float* __restrict__ child,
    float* __restrict__ scL, float* __restrict__ shL)
{
  const int s = blockIdx.x;
  const int t = threadIdx.x;          // 0..255
  __shared__ float xb[512 * 17];      // 34816 B, odd stride -> conflict-free
  __shared__ float Wl[GL * OL];
  __shared__ float bl[OL];
  __shared__ float red[4][2 * OL];

  if (t < GL * OL / 4)
    ((float4*)Wl)[t] = ((const float4*)(W + (size_t)s * GL * OL))[t];
  else if (t >= 160 && t < 165)
    ((float4*)bl)[t - 160] = ((const float4*)(bias + s * OL))[t - 160];

  float sum[OL], ssq[OL];
#pragma unroll
  for (int o = 0; o < OL; o++) { sum[o] = 0.f; ssq[o] = 0.f; }

#pragma unroll 1
  for (int rr = 0; rr < 4; rr++) {
    const float4* src = (const float4*)(x + ((size_t)s * BATCH + rr * 512) * GL);
    float a0[OL], a1[OL];
#pragma unroll
    for (int o = 0; o < OL; o++) { a0[o] = 0.f; a1[o] = 0.f; }

    // ---- K half 0 (k = 0..15): stage 512 rows x 16 floats ----
#pragma unroll
    for (int j = 0; j < 8; j++) {
      const int f2 = t + j * 256;        // 0..2047
      const int r = f2 >> 2, q = f2 & 3;
      float4 v = src[r * 8 + q];         // first half of row r
      float* wp = &xb[r * 17 + q * 4];
      wp[0] = v.x; wp[1] = v.y; wp[2] = v.z; wp[3] = v.w;
    }
    __syncthreads();
    {
      const float* x0 = &xb[t * 17];
      const float* x1 = &xb[(t + 256) * 17];
#pragma unroll
      for (int k = 0; k < 16; k++)
        FMA20x2(x0[k], a0, x1[k], a1, &Wl[k * OL]);
    }
    __syncthreads();

    // ---- K half 1 (k = 16..31) ----
#pragma unroll
    for (int j = 0; j < 8; j++) {
      const int f2 = t + j * 256;
      const int r = f2 >> 2, q = f2 & 3;
      float4 v = src[r * 8 + 4 + q];     // second half of row r
      float* wp = &xb[r * 17 + q * 4];
      wp[0] = v.x; wp[1] = v.y; wp[2] = v.z; wp[3] = v.w;
    }
    __syncthreads();
    {
      const float* x0 = &xb[t * 17];
      const float* x1 = &xb[(t + 256) * 17];
#pragma unroll
      for (int k = 0; k < 16; k++)
        FMA20x2(x0[k], a0, x1[k], a1, &Wl[(16 + k) * OL]);
    }

    const int b0 = rr * 512 + t;         // rows b0 and b0+256
#pragma unroll
    for (int o = 0; o < OL; o++) {
      float h0 = tanh_fast(a0[o] + bl[o]);
      float h1 = tanh_fast(a1[o] + bl[o]);
      child[((size_t)s * OL + o) * BATCH + b0]       = h0;   // coalesced
      child[((size_t)s * OL + o) * BATCH + b0 + 256] = h1;   // coalesced
      sum[o] += h0 + h1;
      ssq[o] = fmaf(h0, h0, fmaf(h1, h1, ssq[o]));
    }
    __syncthreads();   // xb reused next rr
  }

  const int wave = t >> 6, lane = t & 63;
#pragma unroll
  for (int o = 0; o < OL; o++) {
    float s1 = sum[o], s2 = ssq[o];
#pragma unroll
    for (int d = 32; d >= 1; d >>= 1) { s1 += __shfl_xor(s1, d); s2 += __shfl_xor(s2, d); }
    if (lane == 0) { red[wave][o] = s1; red[wave][OL + o] = s2; }
  }
  __syncthreads();
  if (t < 2 * OL) {
    float v = red[0][t] + red[1][t] + red[2][t] + red[3][t];
    red[0][t] = v;
  }
  __syncthreads();
  if (t < OL) {
    float mean = red[0][t] * (1.f / BATCH);
    float var  = red[0][OL + t] * (1.f / BATCH) - mean * mean;
    float rs = rsqrtf(var + EPSBN);
    float sc = g[s * OL + t] * rs;
    scL[s * OL + t] = sc;
    shL[s * OL + t] = be[s * OL + t] - mean * sc;
  }
}

// ---------------- mid: coalesced transposed child reads; transposed hm out --
__global__ __launch_bounds__(256, 2) void k_mid(
    const float* __restrict__ xg, const float* __restrict__ child,
    const float* __restrict__ scL, const float* __restrict__ shL,
    const float* __restrict__ W, const float* __restrict__ bias,
    float* __restrict__ hm, float* __restrict__ mp)
{
  const int chunk = blockIdx.x;
  const int m = blockIdx.y;
  const int t = threadIdx.x;
  const int kq = t >> 6;
  const int lane = t & 63;
  const int b = chunk * 64 + lane;

  __shared__ float Wl[IMID * OM];
  __shared__ float cb[3][64][21];
  __shared__ float scs[CC * OL];
  __shared__ float shs[CC * OL];
  __shared__ float xgb[64 * 69];

  for (int i = t; i < IMID * OM / 4; i += 256)
    ((float4*)Wl)[i] = ((const float4*)(W + (size_t)m * IMID * OM))[i];
  if (t < 80)       ((float4*)scs)[t]      = ((const float4*)(scL + m * CC * OL))[t];
  else if (t < 160) ((float4*)shs)[t - 80] = ((const float4*)(shL + m * CC * OL))[t - 80];

  {
    const float4* gs = (const float4*)(xg + ((size_t)m * BATCH + chunk * 64) * GM);
#pragma unroll
    for (int j = 0; j < 4; j++) {
      const int f = t + j * 256;
      float4 v = gs[f];
      const int r = f >> 4, c4 = (f & 15) << 2;
      float* wp = &xgb[r * 69 + c4];
      wp[0] = v.x; wp[1] = v.y; wp[2] = v.z; wp[3] = v.w;
    }
  }
  __syncthreads();

  float acc[OM];
#pragma unroll
  for (int o = 0; o < OM; o++) acc[o] = 0.f;

  const float* grow = &xgb[lane * 69 + kq * 16];
#pragma unroll
  for (int k = 0; k < 16; k++) {
    FMA20(grow[k], &Wl[(kq * 16 + k) * OM], acc);
  }
#pragma unroll 1
  for (int ci = 0; ci < 4; ci++) {
    const int c = kq * 4 + ci;
    const float* cbase = child + ((size_t)(m * CC + c) * OL) * BATCH + b;
#pragma unroll
    for (int o = 0; o < OL; o++) {
      float v = cbase[(size_t)o * BATCH];
      float xv = fmaf(v, scs[c * OL + o], shs[c * OL + o]);
      FMA20(xv, &Wl[(GM + c * OL + o) * OM], acc);
    }
  }

  if (kq > 0) {
#pragma unroll
    for (int o = 0; o < OM; o++) cb[kq - 1][lane][o] = acc[o];
  }
  __syncthreads();

  if (kq == 0) {
#pragma unroll
    for (int o = 0; o < OM; o++) {
      float v = acc[o] + cb[0][lane][o] + cb[1][lane][o] + cb[2][lane][o] + bias[m * OM + o];
      acc[o] = tanh_fast(v);
    }
#pragma unroll
    for (int o = 0; o < OM; o++)
      hm[((size_t)m * OM + o) * BATCH + b] = acc[o];
#pragma unroll
    for (int o = 0; o < OM; o++) {
      float s1 = acc[o], s2 = acc[o] * acc[o];
#pragma unroll
      for (int d = 32; d >= 1; d >>= 1) { s1 += __shfl_xor(s1, d); s2 += __shfl_xor(s2, d); }
      if (lane == 0) {
        mp[((size_t)m * 32 + chunk) * (2 * OM) + o] = s1;
        mp[((size_t)m * 32 + chunk) * (2 * OM) + OM + o] = s2;
      }
    }
  }
}

// ---------------- mid BN affine finalize (tiny) -----------------------------
__global__ __launch_bounds__(256) void k_midstats(
    const float* __restrict__ mp, const float* __restrict__ g_mid,
    const float* __restrict__ be_mid,
    float* __restrict__ scm, float* __restrict__ shm)
{
  const int e = blockIdx.x * 256 + threadIdx.x;
  if (e >= MM * OM) return;
  const int m = e / OM, o = e % OM;
  float s1 = 0.f, s2 = 0.f;
  for (int c = 0; c < 32; c++) {
    s1 += mp[((size_t)m * 32 + c) * (2 * OM) + o];
    s2 += mp[((size_t)m * 32 + c) * (2 * OM) + OM + o];
  }
  float mean = s1 * (1.f / BATCH);
  float var  = s2 * (1.f / BATCH) - mean * mean;
  float r = rsqrtf(var + EPSBN);
  float sc = g_mid[e] * r;
  scm[e] = sc;
  shm[e] = be_mid[e] - mean * sc;
}

// ---------------- root partial GEMM: K split 16 ways ------------------------
__global__ __launch_bounds__(256, 2) void k_root_partial(
    const float* __restrict__ xr, const float* __restrict__ hm,
    const float* __restrict__ scm, const float* __restrict__ shm,
    const float* __restrict__ W, float* __restrict__ pw)
{
  const int rc = blockIdx.x;      // 0..31
  const int kc = blockIdx.y;      // 0..15
  const int t = threadIdx.x;
  const int w = t >> 6, lane = t & 63;
  const int ob = w * 10;
  const bool full = (w < 3);
  const int b = rc * 64 + lane;
  const int k0 = kc * KCH;

  __shared__ float Wl[KCH * ORR];
  __shared__ float scs[KCH], shs[KCH];

  for (int i = t; i < KCH * ORR; i += 256)
    Wl[i] = W[(size_t)k0 * ORR + i];
  if (t < KCH) {
    const int mi = k0 + t - GR;
    const bool v = (mi >= 0);
    scs[t] = v ? scm[mi] : 0.f;
    shs[t] = v ? shm[mi] : 0.f;
  }
  __syncthreads();

  float acc[10];
#pragma unroll
  for (int j = 0; j < 10; j++) acc[j] = 0.f;

#define FMA10(xs, kk) do { \
    const float2* wr = (const float2*)(Wl + (size_t)(kk) * ORR + ob); \
    float2 w0 = wr[0], w1 = wr[1], w2 = wr[2], w3 = wr[3]; \
    float2 w4 = full ? wr[4] : make_float2(0.f, 0.f); \
    acc[0]=fmaf(xs,w0.x,acc[0]); acc[1]=fmaf(xs,w0.y,acc[1]); \
    acc[2]=fmaf(xs,w1.x,acc[2]); acc[3]=fmaf(xs,w1.y,acc[3]); \
    acc[4]=fmaf(xs,w2.x,acc[4]); acc[5]=fmaf(xs,w2.y,acc[5]); \
    acc[6]=fmaf(xs,w3.x,acc[6]); acc[7]=fmaf(xs,w3.y,acc[7]); \
    acc[8]=fmaf(xs,w4.x,acc[8]); acc[9]=fmaf(xs,w4.y,acc[9]); \
  } while (0)

#pragma unroll 2
  for (int g = 0; g < KCH / 4; g++) {
    const int k = k0 + g * 4;
    float xa[4];
    if (k < GR) {
      float4 xv = *(const float4*)(xr + (size_t)b * GR + k);
      xa[0] = xv.x; xa[1] = xv.y; xa[2] = xv.z; xa[3] = xv.w;
    } else {
      const int mi = k - GR;
      const float* hp = hm + (size_t)mi * BATCH + b;
      const int lk = g * 4;
#pragma unroll
      for (int j = 0; j < 4; j++)
        xa[j] = fmaf(hp[(size_t)j * BATCH], scs[lk + j], shs[lk + j]);
    }
#pragma unroll
    for (int j = 0; j < 4; j++) FMA10(xa[j], g * 4 + j);
  }
#undef FMA10

  const size_t base = ((size_t)kc * BATCH + b) * ORR + ob;
#pragma unroll
  for (int j = 0; j < 10; j++)
    if (j < 8 || full) pw[base + j] = acc[j];
}

// ---------------- root finalize: sum partials + bias + tanh + BN partials ---
__global__ __launch_bounds__(256) void k_rootfinal(
    const float* __restrict__ pw, const float* __restrict__ bias,
    float* __restrict__ hr, float* __restrict__ rp)
{
  const int blk = blockIdx.x;     // 0..31
  const int t = threadIdx.x;
  const int w = t >> 6, lane = t & 63;
  const int ob = w * 10;
  const bool full = (w < 3);
  const int b = blk * 64 + lane;

  float acc[10];
#pragma unroll
  for (int j = 0; j < 10; j++) acc[j] = 0.f;

#pragma unroll 1
  for (int kc = 0; kc < KSPLIT; kc++) {
    const size_t base = ((size_t)kc * BATCH + b) * ORR + ob;
#pragma unroll
    for (int j = 0; j < 10; j++)
      if (j < 8 || full) acc[j] += pw[base + j];
  }

#pragma unroll
  for (int j = 0; j < 10; j++) {
    float bj = (j < 8 || full) ? bias[ob + j] : 0.f;
    acc[j] = tanh_fast(acc[j] + bj);
  }

#pragma unroll
  for (int j = 0; j < 10; j++) {
    float s1 = acc[j], s2 = acc[j] * acc[j];
#pragma unroll
    for (int d = 32; d >= 1; d >>= 1) { s1 += __shfl_xor(s1, d); s2 += __shfl_xor(s2, d); }
    if (lane == 0 && (j < 8 || full)) {
      rp[blk * 76 + ob + j] = s1;
      rp[blk * 76 + ORR + ob + j] = s2;
    }
  }
#pragma unroll
  for (int j = 0; j < 10; j++)
    if (j < 8 || full) hr[(size_t)b * ORR + ob + j] = acc[j];
}

// ---------------- root BN finalize -> output --------------------------------
__global__ __launch_bounds__(256) void k_rootnorm(
    const float* __restrict__ hr, const float* __restrict__ rp,
    const float* __restrict__ g, const float* __restrict__ be,
    float* __restrict__ out)
{
  __shared__ float sc[ORR], sh[ORR];
  const int t = threadIdx.x;
  if (t < ORR) {
    float s1 = 0.f, s2 = 0.f;
    for (int blk = 0; blk < 32; blk++) {
      s1 += rp[blk * 76 + t];
      s2 += rp[blk * 76 + ORR + t];
    }
    float mean = s1 * (1.f / BATCH);
    float var  = s2 * (1.f / BATCH) - mean * mean;
    float r = rsqrtf(var + EPSBN);
    float scv = g[t] * r;
    sc[t] = scv;
    sh[t] = be[t] - mean * scv;
  }
  __syncthreads();
  const int idx = blockIdx.x * 256 + t;   // 304*256 = 77824 exactly
  const int o = idx % ORR;
  out[idx] = hr[idx] * sc[o] + sh[o];
}

extern "C" void kernel_launch(void* const* d_in, const int* in_sizes, int n_in,
                              void* d_out, int out_size, void* d_ws, size_t ws_size,
                              hipStream_t stream) {
  (void)in_sizes; (void)n_in; (void)out_size; (void)ws_size;
  const float* x_leaf  = (const float*)d_in[0];
  const float* x_mid   = (const float*)d_in[1];
  const float* x_root  = (const float*)d_in[2];
  const float* W_leaf  = (const float*)d_in[3];
  const float* b_leaf  = (const float*)d_in[4];
  const float* g_leaf  = (const float*)d_in[5];
  const float* be_leaf = (const float*)d_in[6];
  const float* W_mid   = (const float*)d_in[7];
  const float* b_mid   = (const float*)d_in[8];
  const float* g_mid   = (const float*)d_in[9];
  const float* be_mid  = (const float*)d_in[10];
  const float* W_root  = (const float*)d_in[11];
  const float* b_root  = (const float*)d_in[12];
  const float* g_root  = (const float*)d_in[13];
  const float* be_root = (const float*)d_in[14];
  float* out = (float*)d_out;
  float* ws  = (float*)d_ws;

  float* child = ws;
  float* scL   = ws + OFF_SCL;
  float* shL   = ws + OFF_SHL;
  float* hm    = ws + OFF_HM;
  float* mp    = ws + OFF_MP;
  float* hr    = ws + OFF_HR;
  float* rp    = ws + OFF_RP;
  float* scm   = ws + OFF_SCM;
  float* shm   = ws + OFF_SHM;
  float* pw    = ws + OFF_PW;

  k_leaf<<<SS, 256, 0, stream>>>(x_leaf, W_leaf, b_leaf, g_leaf, be_leaf,
                                 child, scL, shL);
  k_mid<<<dim3(32, MM), 256, 0, stream>>>(x_mid, child, scL, shL, W_mid, b_mid,
                                          hm, mp);
  k_midstats<<<3, 256, 0, stream>>>(mp, g_mid, be_mid, scm, shm);
  k_root_partial<<<dim3(32, KSPLIT), 256, 0, stream>>>(x_root, hm, scm, shm,
                                                       W_root, pw);
  k_rootfinal<<<32, 256, 0, stream>>>(pw, b_root, hr, rp);
  k_rootnorm<<<304, 256, 0, stream>>>(hr, rp, g_root, be_root, out);
}